// Round 1
// baseline (133.195 us; speedup 1.0000x reference)
//
#include <hip/hip_runtime.h>

// SE3 loss: polar-orthogonalize pred_R and quat-derived gt rotation via
// determinant-scaled Newton iteration (converges to the SVD polar factor
// U*V^T), apply the reference's whole-matrix sign(det) flip, then
// mean((P^T G - I)^2) + mean((pred_t - igt_t)^2).

#define NITER 8

__device__ __forceinline__ void polar3(float X[9]) {
    // sign of original determinant (reference multiplies U*V^T by sign(det))
    float d0 = X[0]*(X[4]*X[8]-X[5]*X[7])
             - X[1]*(X[3]*X[8]-X[5]*X[6])
             + X[2]*(X[3]*X[7]-X[4]*X[6]);
#pragma unroll
    for (int it = 0; it < NITER; ++it) {
        // cofactor matrix C (X^{-T} = C / det)
        float C0 = X[4]*X[8]-X[5]*X[7];
        float C1 = X[5]*X[6]-X[3]*X[8];
        float C2 = X[3]*X[7]-X[4]*X[6];
        float C3 = X[2]*X[7]-X[1]*X[8];
        float C4 = X[0]*X[8]-X[2]*X[6];
        float C5 = X[1]*X[6]-X[0]*X[7];
        float C6 = X[1]*X[5]-X[2]*X[4];
        float C7 = X[2]*X[3]-X[0]*X[5];
        float C8 = X[0]*X[4]-X[1]*X[3];
        float det = X[0]*C0 + X[1]*C1 + X[2]*C2;
        float ad  = fabsf(det);
        // g = |det|^{1/3}; gamma = 1/g  (determinant scaling, Byers)
        float g     = __builtin_amdgcn_exp2f(0.33333333f * __builtin_amdgcn_logf(ad));
        float a     = 0.5f * __builtin_amdgcn_rcpf(g);
        float b     = 0.5f * g * __builtin_amdgcn_rcpf(det);
        X[0] = a*X[0] + b*C0;  X[1] = a*X[1] + b*C1;  X[2] = a*X[2] + b*C2;
        X[3] = a*X[3] + b*C3;  X[4] = a*X[4] + b*C4;  X[5] = a*X[5] + b*C5;
        X[6] = a*X[6] + b*C6;  X[7] = a*X[7] + b*C7;  X[8] = a*X[8] + b*C8;
    }
    float s = (d0 > 0.0f) ? 1.0f : ((d0 < 0.0f) ? -1.0f : 0.0f);
#pragma unroll
    for (int k = 0; k < 9; ++k) X[k] *= s;
}

__global__ __launch_bounds__(256) void se3_loss_kernel(
    const float* __restrict__ pred_R,
    const float* __restrict__ pred_t,
    const float* __restrict__ gt,
    float* __restrict__ out, int B)
{
    const float inv9B = 1.0f / (9.0f * (float)B);
    const float inv3B = 1.0f / (3.0f * (float)B);
    float acc = 0.0f;

    int idx    = blockIdx.x * blockDim.x + threadIdx.x;
    int stride = gridDim.x * blockDim.x;
#pragma unroll 1
    for (int i = idx; i < B; i += stride) {
        float P[9];
#pragma unroll
        for (int k = 0; k < 9; ++k) P[k] = pred_R[9*i + k];

        const float* q = gt + 7*i;
        float w = q[0], x = q[1], y = q[2], z = q[3];
        float tx = q[4], ty = q[5], tz = q[6];

        float G[9];
        G[0] = 1.0f - 2.0f*(y*y + z*z);
        G[1] = 2.0f*(x*y - w*z);
        G[2] = 2.0f*(x*z + w*y);
        G[3] = 2.0f*(x*y + w*z);
        G[4] = 1.0f - 2.0f*(x*x + z*z);
        G[5] = 2.0f*(y*z - w*x);
        G[6] = 2.0f*(x*z + w*y) - 4.0f*w*y;   // 2(xz - wy)
        G[7] = 2.0f*(y*z + w*x);
        G[8] = 1.0f - 2.0f*(x*x + y*y);
        // fix G[6] cleanly (avoid the fused trick above being confusing):
        G[6] = 2.0f*(x*z - w*y);

        polar3(P);
        polar3(G);

        // M = P^T * G ; rot = sum((M - I)^2)
        float rot = 0.0f;
#pragma unroll
        for (int im = 0; im < 3; ++im) {
#pragma unroll
            for (int km = 0; km < 3; ++km) {
                float m = P[im]*G[km] + P[3+im]*G[3+km] + P[6+im]*G[6+km];
                if (im == km) m -= 1.0f;
                rot += m*m;
            }
        }

        float dtx = pred_t[3*i+0] - tx;
        float dty = pred_t[3*i+1] - ty;
        float dtz = pred_t[3*i+2] - tz;
        float tl  = dtx*dtx + dty*dty + dtz*dtz;

        acc += rot * inv9B + tl * inv3B;
    }

    // wave reduction (64 lanes)
#pragma unroll
    for (int off = 32; off > 0; off >>= 1)
        acc += __shfl_down(acc, off, 64);

    __shared__ float wsums[4];
    int lane = threadIdx.x & 63;
    int wid  = threadIdx.x >> 6;
    if (lane == 0) wsums[wid] = acc;
    __syncthreads();
    if (threadIdx.x == 0) {
        float t = wsums[0] + wsums[1] + wsums[2] + wsums[3];
        atomicAdd(out, t);
    }
}

extern "C" void kernel_launch(void* const* d_in, const int* in_sizes, int n_in,
                              void* d_out, int out_size, void* d_ws, size_t ws_size,
                              hipStream_t stream) {
    const float* pred_R = (const float*)d_in[0];
    const float* pred_t = (const float*)d_in[1];
    const float* gt     = (const float*)d_in[2];
    float* out = (float*)d_out;
    int B = in_sizes[0] / 9;

    hipMemsetAsync(out, 0, sizeof(float), stream);

    const int block = 256;
    const int grid  = 1024;   // 256k threads, 4 elements/thread grid-stride
    se3_loss_kernel<<<grid, block, 0, stream>>>(pred_R, pred_t, gt, out, B);
}